// Round 3
// baseline (2748.990 us; speedup 1.0000x reference)
//
#include <hip/hip_runtime.h>
#include <math.h>

#define NN 50000
#define NE 1600000
#define KORD 5
#define NB 196          // ceil(NN/256)
#define QTR 12500       // node quarter (k_deg)
#define GE 782          // epi grid: ceil(NN/64)
#define MT 64           // epi node tile
#define NBK 1563        // ceil(NN/32) destination buckets (32 nodes each)
#define NBP 1600        // padded bucket stride
#define NCH 256         // chunks for bucket kernels (fills all CUs)
#define ECH (NE / NCH)  // 6250
#define EC4 (NE / 64)   // 25000 (k_deg chunks)
#define PADE 1800192    // edge buffer capacity (NE + NBK*128, rounded)
#define CVB 1563        // ceil(NN*8/256) cvt blocks

#define SCALE_D 4194304.0f          // 2^22 degree fixed point
#define INV_SCALE_D (1.0f / 4194304.0f)

typedef _Float16 half8 __attribute__((ext_vector_type(8)));
typedef _Float16 half4v __attribute__((ext_vector_type(4)));
typedef float float4v __attribute__((ext_vector_type(4)));

// ---------------- deg: LDS int-fixed-point weighted row histogram ----------
__global__ __launch_bounds__(1024) void k_deg(const int* __restrict__ ei,
                                              const float* __restrict__ ew,
                                              int* __restrict__ deg_g) {
    __shared__ int h[QTR];   // 50 KB
    int q = blockIdx.x >> 6, ch = blockIdx.x & 63;
    for (int i = threadIdx.x; i < QTR; i += 1024) h[i] = 0;
    __syncthreads();
    int base = ch * EC4, lo = q * QTR;
    for (int e = base + threadIdx.x; e < base + EC4; e += 1024) {
        int li = ei[e] - lo;
        if ((unsigned)li < (unsigned)QTR)
            atomicAdd(&h[li], __float2int_rn(ew[e] * SCALE_D));  // ds_add_u32
    }
    __syncthreads();
    int* outp = deg_g + blockIdx.x * QTR;
    for (int i = threadIdx.x; i < QTR; i += 1024) outp[i] = h[i];
}

// merged: blocks [0,NB) compute dis from deg_g; blocks [NB,NB+CVB) convert x->fp16
__global__ __launch_bounds__(256) void k_dis2cvt(const int* __restrict__ deg_g,
                                                 float* __restrict__ dis,
                                                 const float* __restrict__ x,
                                                 _Float16* __restrict__ x16) {
    int bid = blockIdx.x;
    if (bid < NB) {
        int n = bid * 256 + threadIdx.x;
        if (n >= NN) return;
        int q = n / QTR, i = n % QTR;
        const int* p = deg_g + (q * 64) * QTR + i;
        int s = 0;
#pragma unroll
        for (int c = 0; c < 64; c++) s += p[c * QTR];
        float d = (float)s * INV_SCALE_D;
        dis[n] = s > 0 ? rsqrtf(fmaxf(d, 1e-30f)) : 0.f;
    } else {
        int i = (bid - NB) * 256 + threadIdx.x;
        if (i < NN * 8) {
            float4 v = ((const float4*)x)[i];
            half4v h = {(_Float16)v.x, (_Float16)v.y, (_Float16)v.z, (_Float16)v.w};
            *(half4v*)(x16 + i * 4) = h;
        }
    }
}

// ---------------- bucket histogram: bh[ch][b] ----------
__global__ __launch_bounds__(1024) void k_bhist(const int* __restrict__ ei,
                                                int* __restrict__ bh) {
    __shared__ int hist[NBK];
    int ch = blockIdx.x;
    for (int i = threadIdx.x; i < NBK; i += 1024) hist[i] = 0;
    __syncthreads();
    const int* cols = ei + NE;
    int base = ch * ECH;
    for (int e = base + threadIdx.x; e < base + ECH; e += 1024)
        atomicAdd(&hist[cols[e] >> 5], 1);
    __syncthreads();
    int* outp = bh + ch * NBP;
    for (int b = threadIdx.x; b < NBK; b += 1024) outp[b] = hist[b];
}

__global__ __launch_bounds__(256) void k_btot(const int* __restrict__ bh,
                                              int* __restrict__ tot) {
    int b = blockIdx.x * 256 + threadIdx.x;
    if (b >= NBP) return;
    int s = 0;
    if (b < NBK) {
#pragma unroll 8
        for (int ch = 0; ch < NCH; ch++) s += bh[ch * NBP + b];
    }
    tot[b] = s;
}

// one block: pair-compressed exclusive scan of PADDED totals -> off_bk
__global__ __launch_bounds__(1024) void k_bscan1(const int* __restrict__ tot,
                                                 int* __restrict__ off_bk) {
    __shared__ int s[1024];
    int t = threadIdx.x;
    int a0 = (2 * t < NBP) ? tot[2 * t] : 0;
    int a1 = (2 * t + 1 < NBP) ? tot[2 * t + 1] : 0;
    int p0 = (a0 + 127) & ~127;
    int p1 = (a1 + 127) & ~127;
    s[t] = p0 + p1;
    __syncthreads();
    for (int d = 1; d < 1024; d <<= 1) {
        int u = (t >= d) ? s[t - d] : 0;
        __syncthreads();
        s[t] += u;
        __syncthreads();
    }
    int excl = (t == 0) ? 0 : s[t - 1];
    if (2 * t < NBK) off_bk[2 * t] = excl;
    if (2 * t + 1 < NBK) off_bk[2 * t + 1] = excl + p0;
    if (t == 1023) off_bk[NBK] = s[1023];
}

// merged: blocks [0,7) convert bh counts to running cursors; blocks [7,7+NBK)
// fill the pad region of each bucket with zero-weight sentinel edges
__global__ __launch_bounds__(256) void k_curpad(int* __restrict__ bh,
                                                const int* __restrict__ off_bk,
                                                const int* __restrict__ tot,
                                                int2* __restrict__ edges) {
    int bid = blockIdx.x;
    if (bid < 7) {
        int b = bid * 256 + threadIdx.x;
        if (b >= NBK) return;
        int run = off_bk[b];
        for (int ch = 0; ch < NCH; ch++) {
            int v = bh[ch * NBP + b];
            bh[ch * NBP + b] = run;
            run += v;
        }
    } else {
        int b = bid - 7;
        int start = off_bk[b] + tot[b];
        int end = off_bk[b + 1];
        for (int i = start + threadIdx.x; i < end; i += 256)
            edges[i] = make_int2(0, 0);   // r=0, c_local=0, w=0.0f
    }
}

// coarse permute: record = (r | local_c<<16, weight-bits)
__global__ __launch_bounds__(1024) void k_cperm(const int* __restrict__ ei,
                                                const float* __restrict__ ew,
                                                const float* __restrict__ dis,
                                                const int* __restrict__ bh,
                                                int2* __restrict__ edges) {
    __shared__ int cur[NBK];
    int ch = blockIdx.x;
    const int* cp = bh + ch * NBP;
    for (int b = threadIdx.x; b < NBK; b += 1024) cur[b] = cp[b];
    __syncthreads();
    int base = ch * ECH;
    for (int e = base + threadIdx.x; e < base + ECH; e += 1024) {
        int r = ei[e], c = ei[NE + e];
        float w = -dis[r] * ew[e] * dis[c];
        int pos = atomicAdd(&cur[c >> 5], 1);   // ds_add_u32, native
        int packed = (int)((unsigned)r | ((unsigned)(c & 31) << 16));
        edges[pos] = make_int2(packed, __float_as_int(w));
    }
}

// ---------------- spmm: fp16 half8 gathers (16B/lane), fp32 LDS atomics -----
// 4 lanes per edge; 2-deep edge pipeline: records(k+1) || gather(k) || ds(k-1).
// Recurrence folded in: acc init = -prev, weight decode = w*scale, so the
// epilogue is a plain copy.  ds_add_f32 replaces the fixed-point cvt chain.
#define SPMM_DS2(C0, W0, G0, C1, W1, G1)                      \
    {                                                          \
        float* a0 = &acc[C0][sub * 8];                         \
        float* a1 = &acc[C1][sub * 8];                         \
        atomicAdd(a0 + 0, W0 * (float)G0[0]);                  \
        atomicAdd(a0 + 1, W0 * (float)G0[1]);                  \
        atomicAdd(a0 + 2, W0 * (float)G0[2]);                  \
        atomicAdd(a0 + 3, W0 * (float)G0[3]);                  \
        atomicAdd(a0 + 4, W0 * (float)G0[4]);                  \
        atomicAdd(a0 + 5, W0 * (float)G0[5]);                  \
        atomicAdd(a0 + 6, W0 * (float)G0[6]);                  \
        atomicAdd(a0 + 7, W0 * (float)G0[7]);                  \
        atomicAdd(a1 + 0, W1 * (float)G1[0]);                  \
        atomicAdd(a1 + 1, W1 * (float)G1[1]);                  \
        atomicAdd(a1 + 2, W1 * (float)G1[2]);                  \
        atomicAdd(a1 + 3, W1 * (float)G1[3]);                  \
        atomicAdd(a1 + 4, W1 * (float)G1[4]);                  \
        atomicAdd(a1 + 5, W1 * (float)G1[5]);                  \
        atomicAdd(a1 + 6, W1 * (float)G1[6]);                  \
        atomicAdd(a1 + 7, W1 * (float)G1[7]);                  \
    }

__global__ __launch_bounds__(256) void k_spmm(const int* __restrict__ off_bk,
                                              const int2* __restrict__ edges,
                                              const _Float16* __restrict__ vin16,
                                              const float* __restrict__ prev,
                                              float* __restrict__ vout,
                                              _Float16* __restrict__ vout16,
                                              float scale) {
    __shared__ float acc[32][33];
    int b = blockIdx.x;
    {   // init: acc = -prev (exact f32), or 0 for the first Chebyshev step
        int nl = threadIdx.x >> 3, s4 = threadIdx.x & 7;
        int n = (b << 5) + nl;
        float4 p = make_float4(0.f, 0.f, 0.f, 0.f);
        if (prev && n < NN) p = ((const float4*)prev)[n * 8 + s4];
        float* a = &acc[nl][s4 * 4];
        a[0] = -p.x; a[1] = -p.y; a[2] = -p.z; a[3] = -p.w;
    }
    __syncthreads();
    int e0 = off_bk[b], e1 = off_bk[b + 1];
    int group = threadIdx.x >> 2, sub = threadIdx.x & 3;
    const half8* vin8 = (const half8*)vin16;   // 4 half8 per 32-feature row
    int i = e0 + group;
    if (i < e1) {
        int2 R0 = edges[i], R1 = edges[i + 64];
        half8 G0, G1;
        int C0 = 0, C1 = 0;
        float W0 = 0.f, W1 = 0.f;
        bool haveG = false;
        while (true) {
            int ni = i + 128;
            bool moreR = ni < e1;
            int2 N0, N1;
            if (moreR) {                           // stage 1: next records
                N0 = edges[ni]; N1 = edges[ni + 64];
            }
            // stage 2: gather current records (fp16, 16 B/lane, one 64B line/edge)
            half8 g0 = vin8[((unsigned)R0.x & 0xffffu) * 4 + sub];
            half8 g1 = vin8[((unsigned)R1.x & 0xffffu) * 4 + sub];
            // stage 3: ds_add_f32 the previous batch
            if (haveG) SPMM_DS2(C0, W0, G0, C1, W1, G1);
            C0 = (unsigned)R0.x >> 16; C1 = (unsigned)R1.x >> 16;
            W0 = __int_as_float(R0.y) * scale;
            W1 = __int_as_float(R1.y) * scale;
            G0 = g0; G1 = g1;
            haveG = true;
            if (!moreR) break;
            R0 = N0; R1 = N1;
            i = ni;
        }
        SPMM_DS2(C0, W0, G0, C1, W1, G1);
    }
    __syncthreads();
    int base = b << 5;
    int nl = threadIdx.x >> 3, s4 = threadIdx.x & 7;
    int n = base + nl;
    if (n < NN) {
        const float* a = &acc[nl][s4 * 4];
        float4 o = make_float4(a[0], a[1], a[2], a[3]);
        if (vout) ((float4*)vout)[n * 8 + s4] = o;  // fp32 chain (skippable for T4)
        half4v oh = {(_Float16)o.x, (_Float16)o.y, (_Float16)o.z, (_Float16)o.w};
        *(half4v*)(vout16 + n * 32 + s4 * 4) = oh;  // fp16 gather/epi mirror
    }
}

// ---------------- epi1: MFMA GEMM (64 nodes x 64 outs x K=160) + GRU --------
// Inputs are fp16 mirrors; stage half8 directly into LDS (no convert).
__global__ __launch_bounds__(256) void k_epi1(
    const _Float16* __restrict__ x16, const _Float16* __restrict__ t1,
    const _Float16* __restrict__ t2, const _Float16* __restrict__ t3,
    const _Float16* __restrict__ t4, const float* __restrict__ Wx1,
    const float* __restrict__ bx1, const float* __restrict__ bh1,
    float* __restrict__ h, _Float16* __restrict__ h16) {
    __shared__ _Float16 T[5][MT][40];   // 25.6 KB
    __shared__ _Float16 Wt[64][168];    // 21.5 KB, [n][k]
    int n0 = blockIdx.x * MT;
    const _Float16* bufs[5] = {x16, t1, t2, t3, t4};
#pragma unroll
    for (int b = 0; b < 5; b++) {
        for (int idx = threadIdx.x; idx < MT * 4; idx += 256) {
            int r = idx >> 2, c8 = idx & 3;
            int rr = n0 + r; if (rr >= NN) rr = NN - 1;
            half8 v = *(const half8*)(bufs[b] + rr * 32 + c8 * 8);
            *(half8*)&T[b][r][c8 * 8] = v;
        }
    }
    const float* Wz = Wx1;
    const float* Wh = Wx1 + 2 * KORD * 32 * 32;
    for (int idx = threadIdx.x; idx < 160 * 64; idx += 256) {
        int k = idx >> 6, n = idx & 63;
        int b = k >> 5, i = k & 31;
        float w = (n < 32) ? Wz[b * 1024 + i * 32 + n]
                           : Wh[b * 1024 + i * 32 + (n - 32)];
        Wt[n][k] = (_Float16)w;
    }
    __syncthreads();
    int wave = threadIdx.x >> 6;
    int lane = threadIdx.x & 63;
    int lo = lane & 15, quad = lane >> 4;
    float4v acc[4];
#pragma unroll
    for (int t = 0; t < 4; t++) acc[t] = (float4v){0.f, 0.f, 0.f, 0.f};
#pragma unroll
    for (int b = 0; b < 5; b++) {
        half8 a = *(half8*)&T[b][wave * 16 + lo][quad * 8];
#pragma unroll
        for (int t = 0; t < 4; t++) {
            half8 bf = *(half8*)&Wt[t * 16 + lo][b * 32 + quad * 8];
            acc[t] = __builtin_amdgcn_mfma_f32_16x16x32_f16(a, bf, acc[t], 0, 0, 0);
        }
    }
    int nd_base = n0 + wave * 16 + quad * 4;
#pragma unroll
    for (int t = 0; t < 2; t++) {
        int j = t * 16 + lo;
        float bz = bx1[j] + bh1[j];
        float bhb = bx1[64 + j] + bh1[64 + j];
#pragma unroll
        for (int reg = 0; reg < 4; reg++) {
            int nd = nd_base + reg;
            if (nd < NN) {
                float zz = acc[t][reg] + bz;
                float hh = acc[t + 2][reg] + bhb;
                float z = 1.f / (1.f + __expf(-zz));
                float tt = __expf(-2.f * fabsf(hh));
                float ht = copysignf((1.f - tt) / (1.f + tt), hh);
                float v = fmaxf((1.f - z) * ht, 0.f);
                h[nd * 32 + j] = v;
                h16[nd * 32 + j] = (_Float16)v;
            }
        }
    }
}

// ---------------- epi2: MFMA GEMM (64 x 32 x 160) + GRU + final linear ------
__global__ __launch_bounds__(256) void k_epi2(
    const _Float16* __restrict__ h16, const _Float16* __restrict__ t1,
    const _Float16* __restrict__ t2, const _Float16* __restrict__ t3,
    const _Float16* __restrict__ t4, const float* __restrict__ Wx2,
    const float* __restrict__ bx2, const float* __restrict__ bh2,
    const float* __restrict__ Wl, const float* __restrict__ bl,
    float* __restrict__ out) {
    __shared__ _Float16 T[5][MT][40];   // 25.6 KB
    __shared__ _Float16 Wt[32][168];    // 10.8 KB
    __shared__ float H2[MT][17];
    int n0 = blockIdx.x * MT;
    const _Float16* bufs[5] = {h16, t1, t2, t3, t4};
#pragma unroll
    for (int b = 0; b < 5; b++) {
        for (int idx = threadIdx.x; idx < MT * 4; idx += 256) {
            int r = idx >> 2, c8 = idx & 3;
            int rr = n0 + r; if (rr >= NN) rr = NN - 1;
            half8 v = *(const half8*)(bufs[b] + rr * 32 + c8 * 8);
            *(half8*)&T[b][r][c8 * 8] = v;
        }
    }
    const float* Wz = Wx2;
    const float* Wh = Wx2 + 2 * KORD * 32 * 16;
    for (int idx = threadIdx.x; idx < 160 * 32; idx += 256) {
        int k = idx >> 5, n = idx & 31;
        int b = k >> 5, i = k & 31;
        float w = (n < 16) ? Wz[b * 512 + i * 16 + n]
                           : Wh[b * 512 + i * 16 + (n - 16)];
        Wt[n][k] = (_Float16)w;
    }
    __syncthreads();
    int wave = threadIdx.x >> 6;
    int lane = threadIdx.x & 63;
    int lo = lane & 15, quad = lane >> 4;
    float4v acc[2];
    acc[0] = (float4v){0.f, 0.f, 0.f, 0.f};
    acc[1] = (float4v){0.f, 0.f, 0.f, 0.f};
#pragma unroll
    for (int b = 0; b < 5; b++) {
        half8 a = *(half8*)&T[b][wave * 16 + lo][quad * 8];
#pragma unroll
        for (int t = 0; t < 2; t++) {
            half8 bf = *(half8*)&Wt[t * 16 + lo][b * 32 + quad * 8];
            acc[t] = __builtin_amdgcn_mfma_f32_16x16x32_f16(a, bf, acc[t], 0, 0, 0);
        }
    }
    {
        int j = lo;
        float bz = bx2[j] + bh2[j];
        float bhb = bx2[32 + j] + bh2[32 + j];
        int ndl_base = wave * 16 + quad * 4;
#pragma unroll
        for (int reg = 0; reg < 4; reg++) {
            float zz = acc[0][reg] + bz;
            float hh = acc[1][reg] + bhb;
            float z = 1.f / (1.f + __expf(-zz));
            float tt = __expf(-2.f * fabsf(hh));
            float ht = copysignf((1.f - tt) / (1.f + tt), hh);
            H2[ndl_base + reg][j] = fmaxf((1.f - z) * ht, 0.f);
        }
    }
    __syncthreads();
    for (int idx = threadIdx.x; idx < MT * 12; idx += 256) {
        int n = idx / 12, p = idx % 12;
        int gn = n0 + n;
        if (gn < NN) {
            float o = bl[p];
#pragma unroll
            for (int jj = 0; jj < 16; jj++) o = fmaf(H2[n][jj], Wl[p * 16 + jj], o);
            out[gn * 12 + p] = o;
        }
    }
}

// ---------------- launch ----------------

extern "C" void kernel_launch(void* const* d_in, const int* in_sizes, int n_in,
                              void* d_out, int out_size, void* d_ws, size_t ws_size,
                              hipStream_t stream) {
    const float* x   = (const float*)d_in[0];
    const int*   ei  = (const int*)d_in[1];
    const float* ew  = (const float*)d_in[2];
    const float* Wx1 = (const float*)d_in[3];
    const float* bx1 = (const float*)d_in[4];
    const float* bh1 = (const float*)d_in[6];
    const float* Wx2 = (const float*)d_in[7];
    const float* bx2 = (const float*)d_in[8];
    const float* bh2 = (const float*)d_in[10];
    const float* Wl  = (const float*)d_in[11];
    const float* bl  = (const float*)d_in[12];
    float* out = (float*)d_out;

    float* ws     = (float*)d_ws;
    float* dis    = ws;                         // 50048 floats
    int*   bh     = (int*)(ws + 50048);         // NCH*NBP = 409600 ints
    int*   tot    = bh + NCH * NBP;             // NBP ints
    int*   off_bk = tot + NBP;                  // NBP ints
    int2*  edges  = (int2*)(off_bk + NBP);      // PADE int2 (padded buckets)
    float* T1     = (float*)(edges + PADE);     // fp32 chain buffers
    float* T2     = T1 + NN * 32;
    float* T3     = T2 + NN * 32;
    float* hb     = T3 + NN * 32;
    _Float16* x16 = (_Float16*)(hb + NN * 32);  // fp16 mirrors
    _Float16* t1h = x16 + NN * 32;
    _Float16* t2h = t1h + NN * 32;
    _Float16* t3h = t2h + NN * 32;
    _Float16* t4h = t3h + NN * 32;
    _Float16* hbh = t4h + NN * 32;
    int*   deg_g  = (int*)T1;  // 256*QTR ints (T1+T2 region, dead before spmm)

    k_deg    <<<256, 1024, 0, stream>>>(ei, ew, deg_g);
    k_bhist  <<<NCH, 1024, 0, stream>>>(ei, bh);
    k_dis2cvt<<<NB + CVB, 256, 0, stream>>>(deg_g, dis, x, x16);
    k_btot   <<<7, 256, 0, stream>>>(bh, tot);
    k_bscan1 <<<1, 1024, 0, stream>>>(tot, off_bk);
    k_curpad <<<7 + NBK, 256, 0, stream>>>(bh, off_bk, tot, edges);
    k_cperm  <<<NCH, 1024, 0, stream>>>(ei, ew, dis, bh, edges);

    // ---- cell 1: v = x ----
    k_spmm<<<NBK, 256, 0, stream>>>(off_bk, edges, x16, nullptr, T1, t1h, 1.f);
    k_spmm<<<NBK, 256, 0, stream>>>(off_bk, edges, t1h, x,      T2, t2h, 2.f);
    k_spmm<<<NBK, 256, 0, stream>>>(off_bk, edges, t2h, T1,     T3, t3h, 2.f);
    k_spmm<<<NBK, 256, 0, stream>>>(off_bk, edges, t3h, T2, nullptr, t4h, 2.f);
    k_epi1<<<GE, 256, 0, stream>>>(x16, t1h, t2h, t3h, t4h, Wx1, bx1, bh1, hb, hbh);

    // ---- cell 2: v = hb ----
    k_spmm<<<NBK, 256, 0, stream>>>(off_bk, edges, hbh, nullptr, T1, t1h, 1.f);
    k_spmm<<<NBK, 256, 0, stream>>>(off_bk, edges, t1h, hb,     T2, t2h, 2.f);
    k_spmm<<<NBK, 256, 0, stream>>>(off_bk, edges, t2h, T1,     T3, t3h, 2.f);
    k_spmm<<<NBK, 256, 0, stream>>>(off_bk, edges, t3h, T2, nullptr, t4h, 2.f);
    k_epi2<<<GE, 256, 0, stream>>>(hbh, t1h, t2h, t3h, t4h, Wx2, bx2, bh2, Wl, bl, out);
}

// Round 4
// 345.717 us; speedup vs baseline: 7.9516x; 7.9516x over previous
//
#include <hip/hip_runtime.h>
#include <math.h>

#define NN 50000
#define NE 1600000
#define KORD 5
#define NB 196          // ceil(NN/256)
#define QTR 12500       // node quarter (k_deg)
#define GE 782          // epi grid: ceil(NN/64)
#define MT 64           // epi node tile
#define NBK 1563        // ceil(NN/32) destination buckets (32 nodes each)
#define NBP 1600        // padded bucket stride
#define NCH 256         // chunks for bucket kernels (fills all CUs)
#define ECH (NE / NCH)  // 6250
#define EC4 (NE / 64)   // 25000 (k_deg chunks)
#define PADE 1800192    // edge buffer capacity (NE + NBK*128, rounded)
#define CVB 1563        // ceil(NN*8/256) cvt blocks

#define SCALE_W 2097152.0f          // 2^21 spmm fixed point
#define INV_SCALE_W (1.0f / 2097152.0f)
#define SCALE_D 4194304.0f          // 2^22 degree fixed point
#define INV_SCALE_D (1.0f / 4194304.0f)

typedef _Float16 half8 __attribute__((ext_vector_type(8)));
typedef _Float16 half4v __attribute__((ext_vector_type(4)));
typedef float float4v __attribute__((ext_vector_type(4)));

// ---------------- deg: LDS int-fixed-point weighted row histogram ----------
__global__ __launch_bounds__(1024) void k_deg(const int* __restrict__ ei,
                                              const float* __restrict__ ew,
                                              int* __restrict__ deg_g) {
    __shared__ int h[QTR];   // 50 KB
    int q = blockIdx.x >> 6, ch = blockIdx.x & 63;
    for (int i = threadIdx.x; i < QTR; i += 1024) h[i] = 0;
    __syncthreads();
    int base = ch * EC4, lo = q * QTR;
    for (int e = base + threadIdx.x; e < base + EC4; e += 1024) {
        int li = ei[e] - lo;
        if ((unsigned)li < (unsigned)QTR)
            atomicAdd(&h[li], __float2int_rn(ew[e] * SCALE_D));  // ds_add_u32
    }
    __syncthreads();
    int* outp = deg_g + blockIdx.x * QTR;
    for (int i = threadIdx.x; i < QTR; i += 1024) outp[i] = h[i];
}

// merged: blocks [0,NB) compute dis from deg_g; blocks [NB,NB+CVB) convert x->fp16
__global__ __launch_bounds__(256) void k_dis2cvt(const int* __restrict__ deg_g,
                                                 float* __restrict__ dis,
                                                 const float* __restrict__ x,
                                                 _Float16* __restrict__ x16) {
    int bid = blockIdx.x;
    if (bid < NB) {
        int n = bid * 256 + threadIdx.x;
        if (n >= NN) return;
        int q = n / QTR, i = n % QTR;
        const int* p = deg_g + (q * 64) * QTR + i;
        int s = 0;
#pragma unroll
        for (int c = 0; c < 64; c++) s += p[c * QTR];
        float d = (float)s * INV_SCALE_D;
        dis[n] = s > 0 ? rsqrtf(fmaxf(d, 1e-30f)) : 0.f;
    } else {
        int i = (bid - NB) * 256 + threadIdx.x;
        if (i < NN * 8) {
            float4 v = ((const float4*)x)[i];
            half4v h = {(_Float16)v.x, (_Float16)v.y, (_Float16)v.z, (_Float16)v.w};
            *(half4v*)(x16 + i * 4) = h;
        }
    }
}

// ---------------- bucket histogram: bh[ch][b] ----------
__global__ __launch_bounds__(1024) void k_bhist(const int* __restrict__ ei,
                                                int* __restrict__ bh) {
    __shared__ int hist[NBK];
    int ch = blockIdx.x;
    for (int i = threadIdx.x; i < NBK; i += 1024) hist[i] = 0;
    __syncthreads();
    const int* cols = ei + NE;
    int base = ch * ECH;
    for (int e = base + threadIdx.x; e < base + ECH; e += 1024)
        atomicAdd(&hist[cols[e] >> 5], 1);
    __syncthreads();
    int* outp = bh + ch * NBP;
    for (int b = threadIdx.x; b < NBK; b += 1024) outp[b] = hist[b];
}

__global__ __launch_bounds__(256) void k_btot(const int* __restrict__ bh,
                                              int* __restrict__ tot) {
    int b = blockIdx.x * 256 + threadIdx.x;
    if (b >= NBP) return;
    int s = 0;
    if (b < NBK) {
#pragma unroll 8
        for (int ch = 0; ch < NCH; ch++) s += bh[ch * NBP + b];
    }
    tot[b] = s;
}

// one block: pair-compressed exclusive scan of PADDED totals -> off_bk
__global__ __launch_bounds__(1024) void k_bscan1(const int* __restrict__ tot,
                                                 int* __restrict__ off_bk) {
    __shared__ int s[1024];
    int t = threadIdx.x;
    int a0 = (2 * t < NBP) ? tot[2 * t] : 0;
    int a1 = (2 * t + 1 < NBP) ? tot[2 * t + 1] : 0;
    int p0 = (a0 + 127) & ~127;
    int p1 = (a1 + 127) & ~127;
    s[t] = p0 + p1;
    __syncthreads();
    for (int d = 1; d < 1024; d <<= 1) {
        int u = (t >= d) ? s[t - d] : 0;
        __syncthreads();
        s[t] += u;
        __syncthreads();
    }
    int excl = (t == 0) ? 0 : s[t - 1];
    if (2 * t < NBK) off_bk[2 * t] = excl;
    if (2 * t + 1 < NBK) off_bk[2 * t + 1] = excl + p0;
    if (t == 1023) off_bk[NBK] = s[1023];
}

// merged: blocks [0,7) convert bh counts to running cursors; blocks [7,7+NBK)
// fill the pad region of each bucket with zero-weight sentinel edges
__global__ __launch_bounds__(256) void k_curpad(int* __restrict__ bh,
                                                const int* __restrict__ off_bk,
                                                const int* __restrict__ tot,
                                                int2* __restrict__ edges) {
    int bid = blockIdx.x;
    if (bid < 7) {
        int b = bid * 256 + threadIdx.x;
        if (b >= NBK) return;
        int run = off_bk[b];
        for (int ch = 0; ch < NCH; ch++) {
            int v = bh[ch * NBP + b];
            bh[ch * NBP + b] = run;
            run += v;
        }
    } else {
        int b = bid - 7;
        int start = off_bk[b] + tot[b];
        int end = off_bk[b + 1];
        for (int i = start + threadIdx.x; i < end; i += 256)
            edges[i] = make_int2(0, 0);   // r=0, c_local=0, w=0.0f
    }
}

// coarse permute: record = (r | local_c<<16, weight-bits)
__global__ __launch_bounds__(1024) void k_cperm(const int* __restrict__ ei,
                                                const float* __restrict__ ew,
                                                const float* __restrict__ dis,
                                                const int* __restrict__ bh,
                                                int2* __restrict__ edges) {
    __shared__ int cur[NBK];
    int ch = blockIdx.x;
    const int* cp = bh + ch * NBP;
    for (int b = threadIdx.x; b < NBK; b += 1024) cur[b] = cp[b];
    __syncthreads();
    int base = ch * ECH;
    for (int e = base + threadIdx.x; e < base + ECH; e += 1024) {
        int r = ei[e], c = ei[NE + e];
        float w = -dis[r] * ew[e] * dis[c];
        int pos = atomicAdd(&cur[c >> 5], 1);   // ds_add_u32, native
        int packed = (int)((unsigned)r | ((unsigned)(c & 31) << 16));
        edges[pos] = make_int2(packed, __float_as_int(w));
    }
}

// ---------------- spmm: fp16 half8 gathers (16B/lane), int fixed-point LDS --
// 4 lanes per edge; 2-deep edge pipeline: records(k+1) || gather(k) || ds(k-1).
// NOTE: accumulator must be INT fixed-point — fp32 atomicAdd on LDS lowers to
// a CAS retry loop on hipcc (measured 15x slowdown, waves idle on lgkm).
// ds_add_u32 is native fire-and-forget.  Recurrence folded in: acc init =
// round(-prev*2^21), scale folded into weight decode, epilogue = convert-copy.
#define SPMM_DS2(C0, W0, G0, C1, W1, G1)                       \
    {                                                          \
        int* a0 = &acc[C0][sub * 8];                           \
        int* a1 = &acc[C1][sub * 8];                           \
        atomicAdd(a0 + 0, __float2int_rn(W0 * (float)G0[0]));  \
        atomicAdd(a0 + 1, __float2int_rn(W0 * (float)G0[1]));  \
        atomicAdd(a0 + 2, __float2int_rn(W0 * (float)G0[2]));  \
        atomicAdd(a0 + 3, __float2int_rn(W0 * (float)G0[3]));  \
        atomicAdd(a0 + 4, __float2int_rn(W0 * (float)G0[4]));  \
        atomicAdd(a0 + 5, __float2int_rn(W0 * (float)G0[5]));  \
        atomicAdd(a0 + 6, __float2int_rn(W0 * (float)G0[6]));  \
        atomicAdd(a0 + 7, __float2int_rn(W0 * (float)G0[7]));  \
        atomicAdd(a1 + 0, __float2int_rn(W1 * (float)G1[0]));  \
        atomicAdd(a1 + 1, __float2int_rn(W1 * (float)G1[1]));  \
        atomicAdd(a1 + 2, __float2int_rn(W1 * (float)G1[2]));  \
        atomicAdd(a1 + 3, __float2int_rn(W1 * (float)G1[3]));  \
        atomicAdd(a1 + 4, __float2int_rn(W1 * (float)G1[4]));  \
        atomicAdd(a1 + 5, __float2int_rn(W1 * (float)G1[5]));  \
        atomicAdd(a1 + 6, __float2int_rn(W1 * (float)G1[6]));  \
        atomicAdd(a1 + 7, __float2int_rn(W1 * (float)G1[7]));  \
    }

__global__ __launch_bounds__(256) void k_spmm(const int* __restrict__ off_bk,
                                              const int2* __restrict__ edges,
                                              const _Float16* __restrict__ vin16,
                                              const float* __restrict__ prev,
                                              float* __restrict__ vout,
                                              _Float16* __restrict__ vout16,
                                              float scale) {
    __shared__ int acc[32][33];
    int b = blockIdx.x;
    {   // init: acc = round(-prev * 2^21), or 0 for the first Chebyshev step
        int nl = threadIdx.x >> 3, s4 = threadIdx.x & 7;
        int n = (b << 5) + nl;
        float4 p = make_float4(0.f, 0.f, 0.f, 0.f);
        if (prev && n < NN) p = ((const float4*)prev)[n * 8 + s4];
        int* a = &acc[nl][s4 * 4];
        a[0] = __float2int_rn(-p.x * SCALE_W);
        a[1] = __float2int_rn(-p.y * SCALE_W);
        a[2] = __float2int_rn(-p.z * SCALE_W);
        a[3] = __float2int_rn(-p.w * SCALE_W);
    }
    __syncthreads();
    int e0 = off_bk[b], e1 = off_bk[b + 1];
    int group = threadIdx.x >> 2, sub = threadIdx.x & 3;
    const half8* vin8 = (const half8*)vin16;   // 4 half8 per 32-feature row
    float wscale = scale * SCALE_W;            // fold scale into weight decode
    int i = e0 + group;
    if (i < e1) {
        int2 R0 = edges[i], R1 = edges[i + 64];
        half8 G0, G1;
        int C0 = 0, C1 = 0;
        float W0 = 0.f, W1 = 0.f;
        bool haveG = false;
        while (true) {
            int ni = i + 128;
            bool moreR = ni < e1;
            int2 N0, N1;
            if (moreR) {                           // stage 1: next records
                N0 = edges[ni]; N1 = edges[ni + 64];
            }
            // stage 2: gather current records (fp16, 16 B/lane, one 64B line/edge)
            half8 g0 = vin8[((unsigned)R0.x & 0xffffu) * 4 + sub];
            half8 g1 = vin8[((unsigned)R1.x & 0xffffu) * 4 + sub];
            // stage 3: ds_add_u32 the previous batch
            if (haveG) SPMM_DS2(C0, W0, G0, C1, W1, G1);
            C0 = (unsigned)R0.x >> 16; C1 = (unsigned)R1.x >> 16;
            W0 = __int_as_float(R0.y) * wscale;
            W1 = __int_as_float(R1.y) * wscale;
            G0 = g0; G1 = g1;
            haveG = true;
            if (!moreR) break;
            R0 = N0; R1 = N1;
            i = ni;
        }
        SPMM_DS2(C0, W0, G0, C1, W1, G1);
    }
    __syncthreads();
    int base = b << 5;
    int nl = threadIdx.x >> 3, s4 = threadIdx.x & 7;
    int n = base + nl;
    if (n < NN) {
        const int* a = &acc[nl][s4 * 4];
        float4 o = make_float4((float)a[0] * INV_SCALE_W, (float)a[1] * INV_SCALE_W,
                               (float)a[2] * INV_SCALE_W, (float)a[3] * INV_SCALE_W);
        if (vout) ((float4*)vout)[n * 8 + s4] = o;  // fp32 chain (skippable for T4)
        half4v oh = {(_Float16)o.x, (_Float16)o.y, (_Float16)o.z, (_Float16)o.w};
        *(half4v*)(vout16 + n * 32 + s4 * 4) = oh;  // fp16 gather/epi mirror
    }
}

// ---------------- epi1: MFMA GEMM (64 nodes x 64 outs x K=160) + GRU --------
// Inputs are fp16 mirrors; stage half8 directly into LDS (no convert).
__global__ __launch_bounds__(256) void k_epi1(
    const _Float16* __restrict__ x16, const _Float16* __restrict__ t1,
    const _Float16* __restrict__ t2, const _Float16* __restrict__ t3,
    const _Float16* __restrict__ t4, const float* __restrict__ Wx1,
    const float* __restrict__ bx1, const float* __restrict__ bh1,
    float* __restrict__ h, _Float16* __restrict__ h16) {
    __shared__ _Float16 T[5][MT][40];   // 25.6 KB
    __shared__ _Float16 Wt[64][168];    // 21.5 KB, [n][k]
    int n0 = blockIdx.x * MT;
    const _Float16* bufs[5] = {x16, t1, t2, t3, t4};
#pragma unroll
    for (int b = 0; b < 5; b++) {
        for (int idx = threadIdx.x; idx < MT * 4; idx += 256) {
            int r = idx >> 2, c8 = idx & 3;
            int rr = n0 + r; if (rr >= NN) rr = NN - 1;
            half8 v = *(const half8*)(bufs[b] + rr * 32 + c8 * 8);
            *(half8*)&T[b][r][c8 * 8] = v;
        }
    }
    const float* Wz = Wx1;
    const float* Wh = Wx1 + 2 * KORD * 32 * 32;
    for (int idx = threadIdx.x; idx < 160 * 64; idx += 256) {
        int k = idx >> 6, n = idx & 63;
        int b = k >> 5, i = k & 31;
        float w = (n < 32) ? Wz[b * 1024 + i * 32 + n]
                           : Wh[b * 1024 + i * 32 + (n - 32)];
        Wt[n][k] = (_Float16)w;
    }
    __syncthreads();
    int wave = threadIdx.x >> 6;
    int lane = threadIdx.x & 63;
    int lo = lane & 15, quad = lane >> 4;
    float4v acc[4];
#pragma unroll
    for (int t = 0; t < 4; t++) acc[t] = (float4v){0.f, 0.f, 0.f, 0.f};
#pragma unroll
    for (int b = 0; b < 5; b++) {
        half8 a = *(half8*)&T[b][wave * 16 + lo][quad * 8];
#pragma unroll
        for (int t = 0; t < 4; t++) {
            half8 bf = *(half8*)&Wt[t * 16 + lo][b * 32 + quad * 8];
            acc[t] = __builtin_amdgcn_mfma_f32_16x16x32_f16(a, bf, acc[t], 0, 0, 0);
        }
    }
    int nd_base = n0 + wave * 16 + quad * 4;
#pragma unroll
    for (int t = 0; t < 2; t++) {
        int j = t * 16 + lo;
        float bz = bx1[j] + bh1[j];
        float bhb = bx1[64 + j] + bh1[64 + j];
#pragma unroll
        for (int reg = 0; reg < 4; reg++) {
            int nd = nd_base + reg;
            if (nd < NN) {
                float zz = acc[t][reg] + bz;
                float hh = acc[t + 2][reg] + bhb;
                float z = 1.f / (1.f + __expf(-zz));
                float tt = __expf(-2.f * fabsf(hh));
                float ht = copysignf((1.f - tt) / (1.f + tt), hh);
                float v = fmaxf((1.f - z) * ht, 0.f);
                h[nd * 32 + j] = v;
                h16[nd * 32 + j] = (_Float16)v;
            }
        }
    }
}

// ---------------- epi2: MFMA GEMM (64 x 32 x 160) + GRU + final linear ------
__global__ __launch_bounds__(256) void k_epi2(
    const _Float16* __restrict__ h16, const _Float16* __restrict__ t1,
    const _Float16* __restrict__ t2, const _Float16* __restrict__ t3,
    const _Float16* __restrict__ t4, const float* __restrict__ Wx2,
    const float* __restrict__ bx2, const float* __restrict__ bh2,
    const float* __restrict__ Wl, const float* __restrict__ bl,
    float* __restrict__ out) {
    __shared__ _Float16 T[5][MT][40];   // 25.6 KB
    __shared__ _Float16 Wt[32][168];    // 10.8 KB
    __shared__ float H2[MT][17];
    int n0 = blockIdx.x * MT;
    const _Float16* bufs[5] = {h16, t1, t2, t3, t4};
#pragma unroll
    for (int b = 0; b < 5; b++) {
        for (int idx = threadIdx.x; idx < MT * 4; idx += 256) {
            int r = idx >> 2, c8 = idx & 3;
            int rr = n0 + r; if (rr >= NN) rr = NN - 1;
            half8 v = *(const half8*)(bufs[b] + rr * 32 + c8 * 8);
            *(half8*)&T[b][r][c8 * 8] = v;
        }
    }
    const float* Wz = Wx2;
    const float* Wh = Wx2 + 2 * KORD * 32 * 16;
    for (int idx = threadIdx.x; idx < 160 * 32; idx += 256) {
        int k = idx >> 5, n = idx & 31;
        int b = k >> 5, i = k & 31;
        float w = (n < 16) ? Wz[b * 512 + i * 16 + n]
                           : Wh[b * 512 + i * 16 + (n - 16)];
        Wt[n][k] = (_Float16)w;
    }
    __syncthreads();
    int wave = threadIdx.x >> 6;
    int lane = threadIdx.x & 63;
    int lo = lane & 15, quad = lane >> 4;
    float4v acc[2];
    acc[0] = (float4v){0.f, 0.f, 0.f, 0.f};
    acc[1] = (float4v){0.f, 0.f, 0.f, 0.f};
#pragma unroll
    for (int b = 0; b < 5; b++) {
        half8 a = *(half8*)&T[b][wave * 16 + lo][quad * 8];
#pragma unroll
        for (int t = 0; t < 2; t++) {
            half8 bf = *(half8*)&Wt[t * 16 + lo][b * 32 + quad * 8];
            acc[t] = __builtin_amdgcn_mfma_f32_16x16x32_f16(a, bf, acc[t], 0, 0, 0);
        }
    }
    {
        int j = lo;
        float bz = bx2[j] + bh2[j];
        float bhb = bx2[32 + j] + bh2[32 + j];
        int ndl_base = wave * 16 + quad * 4;
#pragma unroll
        for (int reg = 0; reg < 4; reg++) {
            float zz = acc[0][reg] + bz;
            float hh = acc[1][reg] + bhb;
            float z = 1.f / (1.f + __expf(-zz));
            float tt = __expf(-2.f * fabsf(hh));
            float ht = copysignf((1.f - tt) / (1.f + tt), hh);
            H2[ndl_base + reg][j] = fmaxf((1.f - z) * ht, 0.f);
        }
    }
    __syncthreads();
    for (int idx = threadIdx.x; idx < MT * 12; idx += 256) {
        int n = idx / 12, p = idx % 12;
        int gn = n0 + n;
        if (gn < NN) {
            float o = bl[p];
#pragma unroll
            for (int jj = 0; jj < 16; jj++) o = fmaf(H2[n][jj], Wl[p * 16 + jj], o);
            out[gn * 12 + p] = o;
        }
    }
}

// ---------------- launch ----------------

extern "C" void kernel_launch(void* const* d_in, const int* in_sizes, int n_in,
                              void* d_out, int out_size, void* d_ws, size_t ws_size,
                              hipStream_t stream) {
    const float* x   = (const float*)d_in[0];
    const int*   ei  = (const int*)d_in[1];
    const float* ew  = (const float*)d_in[2];
    const float* Wx1 = (const float*)d_in[3];
    const float* bx1 = (const float*)d_in[4];
    const float* bh1 = (const float*)d_in[6];
    const float* Wx2 = (const float*)d_in[7];
    const float* bx2 = (const float*)d_in[8];
    const float* bh2 = (const float*)d_in[10];
    const float* Wl  = (const float*)d_in[11];
    const float* bl  = (const float*)d_in[12];
    float* out = (float*)d_out;

    float* ws     = (float*)d_ws;
    float* dis    = ws;                         // 50048 floats
    int*   bh     = (int*)(ws + 50048);         // NCH*NBP = 409600 ints
    int*   tot    = bh + NCH * NBP;             // NBP ints
    int*   off_bk = tot + NBP;                  // NBP ints
    int2*  edges  = (int2*)(off_bk + NBP);      // PADE int2 (padded buckets)
    float* T1     = (float*)(edges + PADE);     // fp32 chain buffers
    float* T2     = T1 + NN * 32;
    float* T3     = T2 + NN * 32;
    float* hb     = T3 + NN * 32;
    _Float16* x16 = (_Float16*)(hb + NN * 32);  // fp16 mirrors
    _Float16* t1h = x16 + NN * 32;
    _Float16* t2h = t1h + NN * 32;
    _Float16* t3h = t2h + NN * 32;
    _Float16* t4h = t3h + NN * 32;
    _Float16* hbh = t4h + NN * 32;
    int*   deg_g  = (int*)T1;  // 256*QTR ints (T1+T2 region, dead before spmm)

    k_deg    <<<256, 1024, 0, stream>>>(ei, ew, deg_g);
    k_bhist  <<<NCH, 1024, 0, stream>>>(ei, bh);
    k_dis2cvt<<<NB + CVB, 256, 0, stream>>>(deg_g, dis, x, x16);
    k_btot   <<<7, 256, 0, stream>>>(bh, tot);
    k_bscan1 <<<1, 1024, 0, stream>>>(tot, off_bk);
    k_curpad <<<7 + NBK, 256, 0, stream>>>(bh, off_bk, tot, edges);
    k_cperm  <<<NCH, 1024, 0, stream>>>(ei, ew, dis, bh, edges);

    // ---- cell 1: v = x ----
    k_spmm<<<NBK, 256, 0, stream>>>(off_bk, edges, x16, nullptr, T1, t1h, 1.f);
    k_spmm<<<NBK, 256, 0, stream>>>(off_bk, edges, t1h, x,      T2, t2h, 2.f);
    k_spmm<<<NBK, 256, 0, stream>>>(off_bk, edges, t2h, T1,     T3, t3h, 2.f);
    k_spmm<<<NBK, 256, 0, stream>>>(off_bk, edges, t3h, T2, nullptr, t4h, 2.f);
    k_epi1<<<GE, 256, 0, stream>>>(x16, t1h, t2h, t3h, t4h, Wx1, bx1, bh1, hb, hbh);

    // ---- cell 2: v = hb ----
    k_spmm<<<NBK, 256, 0, stream>>>(off_bk, edges, hbh, nullptr, T1, t1h, 1.f);
    k_spmm<<<NBK, 256, 0, stream>>>(off_bk, edges, t1h, hb,     T2, t2h, 2.f);
    k_spmm<<<NBK, 256, 0, stream>>>(off_bk, edges, t2h, T1,     T3, t3h, 2.f);
    k_spmm<<<NBK, 256, 0, stream>>>(off_bk, edges, t3h, T2, nullptr, t4h, 2.f);
    k_epi2<<<GE, 256, 0, stream>>>(hbh, t1h, t2h, t3h, t4h, Wx2, bx2, bh2, Wl, bl, out);
}

// Round 5
// 337.940 us; speedup vs baseline: 8.1346x; 1.0230x over previous
//
#include <hip/hip_runtime.h>
#include <math.h>

#define NN 50000
#define NE 1600000
#define KORD 5
#define NB 196          // ceil(NN/256)
#define QTR 12500       // node quarter (k_deg)
#define GE 782          // epi grid: ceil(NN/64)
#define MT 64           // epi node tile
#define NBK 1563        // ceil(NN/32) destination buckets (32 nodes each)
#define NBP 1600        // padded bucket stride
#define NCH 256         // chunks for bucket kernels (fills all CUs)
#define ECH (NE / NCH)  // 6250
#define EC4 (NE / 64)   // 25000 (k_deg chunks)
#define PADE 1800192    // edge buffer capacity (NE + NBK*128, rounded)
#define CVB 1563        // ceil(NN*8/256) cvt blocks

#define SCALE_W 2097152.0f          // 2^21 spmm fixed point
#define INV_SCALE_W (1.0f / 2097152.0f)
#define SCALE_D 4194304.0f          // 2^22 degree fixed point
#define INV_SCALE_D (1.0f / 4194304.0f)

typedef _Float16 half8 __attribute__((ext_vector_type(8)));
typedef _Float16 half4v __attribute__((ext_vector_type(4)));
typedef float float4v __attribute__((ext_vector_type(4)));

// ---------------- deg + bhist fused (both read the edge list) --------------
// blocks [0,256): weighted row histogram quarters (deg_g)
// blocks [256,512): destination bucket histogram (bh)
__global__ __launch_bounds__(1024) void k_degbh(const int* __restrict__ ei,
                                                const float* __restrict__ ew,
                                                int* __restrict__ deg_g,
                                                int* __restrict__ bh) {
    __shared__ int sbuf[QTR];   // 50 KB (bhist uses first NBK)
    int bid = blockIdx.x;
    if (bid < 256) {
        int q = bid >> 6, ch = bid & 63;
        for (int i = threadIdx.x; i < QTR; i += 1024) sbuf[i] = 0;
        __syncthreads();
        int base = ch * EC4, lo = q * QTR;
        for (int e = base + threadIdx.x; e < base + EC4; e += 1024) {
            int li = ei[e] - lo;
            if ((unsigned)li < (unsigned)QTR)
                atomicAdd(&sbuf[li], __float2int_rn(ew[e] * SCALE_D));  // ds_add_u32
        }
        __syncthreads();
        int* outp = deg_g + bid * QTR;
        for (int i = threadIdx.x; i < QTR; i += 1024) outp[i] = sbuf[i];
    } else {
        int ch = bid - 256;
        for (int i = threadIdx.x; i < NBK; i += 1024) sbuf[i] = 0;
        __syncthreads();
        const int* cols = ei + NE;
        int base = ch * ECH;
        for (int e = base + threadIdx.x; e < base + ECH; e += 1024)
            atomicAdd(&sbuf[cols[e] >> 5], 1);
        __syncthreads();
        int* outp = bh + ch * NBP;
        for (int b = threadIdx.x; b < NBK; b += 1024) outp[b] = sbuf[b];
    }
}

// ---------------- btot + dis + cvt fused (all deps ready after k_degbh) ----
// blocks [0,7): bucket totals; [7,7+NB): dis = rsqrt(deg); rest: x -> fp16
__global__ __launch_bounds__(256) void k_btotdiscvt(const int* __restrict__ bh,
                                                    int* __restrict__ tot,
                                                    const int* __restrict__ deg_g,
                                                    float* __restrict__ dis,
                                                    const float* __restrict__ x,
                                                    _Float16* __restrict__ x16) {
    int bid = blockIdx.x;
    if (bid < 7) {
        int b = bid * 256 + threadIdx.x;
        if (b >= NBP) return;
        int s = 0;
        if (b < NBK) {
#pragma unroll 8
            for (int ch = 0; ch < NCH; ch++) s += bh[ch * NBP + b];
        }
        tot[b] = s;
    } else if (bid < 7 + NB) {
        int n = (bid - 7) * 256 + threadIdx.x;
        if (n >= NN) return;
        int q = n / QTR, i = n % QTR;
        const int* p = deg_g + (q * 64) * QTR + i;
        int s = 0;
#pragma unroll
        for (int c = 0; c < 64; c++) s += p[c * QTR];
        float d = (float)s * INV_SCALE_D;
        dis[n] = s > 0 ? rsqrtf(fmaxf(d, 1e-30f)) : 0.f;
    } else {
        int i = (bid - 7 - NB) * 256 + threadIdx.x;
        if (i < NN * 8) {
            float4 v = ((const float4*)x)[i];
            half4v h = {(_Float16)v.x, (_Float16)v.y, (_Float16)v.z, (_Float16)v.w};
            *(half4v*)(x16 + i * 4) = h;
        }
    }
}

// one block: pair-compressed exclusive scan of PADDED totals -> off_bk
__global__ __launch_bounds__(1024) void k_bscan1(const int* __restrict__ tot,
                                                 int* __restrict__ off_bk) {
    __shared__ int s[1024];
    int t = threadIdx.x;
    int a0 = (2 * t < NBP) ? tot[2 * t] : 0;
    int a1 = (2 * t + 1 < NBP) ? tot[2 * t + 1] : 0;
    int p0 = (a0 + 127) & ~127;
    int p1 = (a1 + 127) & ~127;
    s[t] = p0 + p1;
    __syncthreads();
    for (int d = 1; d < 1024; d <<= 1) {
        int u = (t >= d) ? s[t - d] : 0;
        __syncthreads();
        s[t] += u;
        __syncthreads();
    }
    int excl = (t == 0) ? 0 : s[t - 1];
    if (2 * t < NBK) off_bk[2 * t] = excl;
    if (2 * t + 1 < NBK) off_bk[2 * t + 1] = excl + p0;
    if (t == 1023) off_bk[NBK] = s[1023];
}

// merged: blocks [0,7) convert bh counts to running cursors; blocks [7,7+NBK)
// fill the pad region of each bucket with zero-weight sentinel edges
__global__ __launch_bounds__(256) void k_curpad(int* __restrict__ bh,
                                                const int* __restrict__ off_bk,
                                                const int* __restrict__ tot,
                                                int2* __restrict__ edges) {
    int bid = blockIdx.x;
    if (bid < 7) {
        int b = bid * 256 + threadIdx.x;
        if (b >= NBK) return;
        int run = off_bk[b];
        for (int ch = 0; ch < NCH; ch++) {
            int v = bh[ch * NBP + b];
            bh[ch * NBP + b] = run;
            run += v;
        }
    } else {
        int b = bid - 7;
        int start = off_bk[b] + tot[b];
        int end = off_bk[b + 1];
        for (int i = start + threadIdx.x; i < end; i += 256)
            edges[i] = make_int2(0, 0);   // r=0, c_local=0, w=0.0f
    }
}

// coarse permute: record = (r | local_c<<16, weight-bits)
__global__ __launch_bounds__(1024) void k_cperm(const int* __restrict__ ei,
                                                const float* __restrict__ ew,
                                                const float* __restrict__ dis,
                                                const int* __restrict__ bh,
                                                int2* __restrict__ edges) {
    __shared__ int cur[NBK];
    int ch = blockIdx.x;
    const int* cp = bh + ch * NBP;
    for (int b = threadIdx.x; b < NBK; b += 1024) cur[b] = cp[b];
    __syncthreads();
    int base = ch * ECH;
    for (int e = base + threadIdx.x; e < base + ECH; e += 1024) {
        int r = ei[e], c = ei[NE + e];
        float w = -dis[r] * ew[e] * dis[c];
        int pos = atomicAdd(&cur[c >> 5], 1);   // ds_add_u32, native
        int packed = (int)((unsigned)r | ((unsigned)(c & 31) << 16));
        edges[pos] = make_int2(packed, __float_as_int(w));
    }
}

// ---------------- spmm: fp16 half8 gathers, int fixed-point LDS ------------
// 4 lanes per edge; DEPTH-4 pipeline: records prefetched 3 iters ahead,
// gathers issued 2 iters ahead, DS on current — doubles the latency slack on
// the random gathers vs the old depth-2 scheme.
// NOTE: accumulator must be INT fixed-point — fp32 atomicAdd on LDS lowers to
// a CAS retry loop on hipcc (measured 15x slowdown).  ds_add_u32 is native.
#define SPMM_DS2(C0, W0, G0, C1, W1, G1)                       \
    {                                                          \
        int* a0 = &acc[C0][sub * 8];                           \
        int* a1 = &acc[C1][sub * 8];                           \
        atomicAdd(a0 + 0, __float2int_rn(W0 * (float)G0[0]));  \
        atomicAdd(a0 + 1, __float2int_rn(W0 * (float)G0[1]));  \
        atomicAdd(a0 + 2, __float2int_rn(W0 * (float)G0[2]));  \
        atomicAdd(a0 + 3, __float2int_rn(W0 * (float)G0[3]));  \
        atomicAdd(a0 + 4, __float2int_rn(W0 * (float)G0[4]));  \
        atomicAdd(a0 + 5, __float2int_rn(W0 * (float)G0[5]));  \
        atomicAdd(a0 + 6, __float2int_rn(W0 * (float)G0[6]));  \
        atomicAdd(a0 + 7, __float2int_rn(W0 * (float)G0[7]));  \
        atomicAdd(a1 + 0, __float2int_rn(W1 * (float)G1[0]));  \
        atomicAdd(a1 + 1, __float2int_rn(W1 * (float)G1[1]));  \
        atomicAdd(a1 + 2, __float2int_rn(W1 * (float)G1[2]));  \
        atomicAdd(a1 + 3, __float2int_rn(W1 * (float)G1[3]));  \
        atomicAdd(a1 + 4, __float2int_rn(W1 * (float)G1[4]));  \
        atomicAdd(a1 + 5, __float2int_rn(W1 * (float)G1[5]));  \
        atomicAdd(a1 + 6, __float2int_rn(W1 * (float)G1[6]));  \
        atomicAdd(a1 + 7, __float2int_rn(W1 * (float)G1[7]));  \
    }

__global__ __launch_bounds__(256) void k_spmm(const int* __restrict__ off_bk,
                                              const int2* __restrict__ edges,
                                              const _Float16* __restrict__ vin16,
                                              const float* __restrict__ prev,
                                              float* __restrict__ vout,
                                              _Float16* __restrict__ vout16,
                                              float scale) {
    __shared__ int acc[32][33];
    int b = blockIdx.x;
    {   // init: acc = round(-prev * 2^21), or 0 for the first Chebyshev step
        int nl = threadIdx.x >> 3, s4 = threadIdx.x & 7;
        int n = (b << 5) + nl;
        float4 p = make_float4(0.f, 0.f, 0.f, 0.f);
        if (prev && n < NN) p = ((const float4*)prev)[n * 8 + s4];
        int* a = &acc[nl][s4 * 4];
        a[0] = __float2int_rn(-p.x * SCALE_W);
        a[1] = __float2int_rn(-p.y * SCALE_W);
        a[2] = __float2int_rn(-p.z * SCALE_W);
        a[3] = __float2int_rn(-p.w * SCALE_W);
    }
    __syncthreads();
    int e0 = off_bk[b], e1 = off_bk[b + 1];
    int group = threadIdx.x >> 2, sub = threadIdx.x & 3;
    const half8* vin8 = (const half8*)vin16;   // 4 half8 per 32-feature row
    float wscale = scale * SCALE_W;            // fold scale into weight decode
    int nit = (e1 - e0) >> 7;                  // bucket sizes are 128-multiples
    if (nit > 0) {
        int i = e0 + group;                    // this group's edges: i, i+64
        // record window (iters k, k+1, k+2) and gather window (k, k+1)
        int2 Ra0 = edges[i], Ra1 = edges[i + 64];
        int2 Rb0 = make_int2(0, 0), Rb1 = make_int2(0, 0);
        int2 Rc0 = make_int2(0, 0), Rc1 = make_int2(0, 0);
        if (nit > 1) { Rb0 = edges[i + 128]; Rb1 = edges[i + 192]; }
        if (nit > 2) { Rc0 = edges[i + 256]; Rc1 = edges[i + 320]; }
        half8 Ga0 = vin8[((unsigned)Ra0.x & 0xffffu) * 4 + sub];
        half8 Ga1 = vin8[((unsigned)Ra1.x & 0xffffu) * 4 + sub];
        half8 Gb0 = {}, Gb1 = {};
        if (nit > 1) {
            Gb0 = vin8[((unsigned)Rb0.x & 0xffffu) * 4 + sub];
            Gb1 = vin8[((unsigned)Rb1.x & 0xffffu) * 4 + sub];
        }
        for (int k = 0; k < nit; k++) {
            // stage 1: records for iter k+3
            int2 Rd0 = make_int2(0, 0), Rd1 = make_int2(0, 0);
            if (k + 3 < nit) { Rd0 = edges[i + 384]; Rd1 = edges[i + 448]; }
            // stage 2: gathers for iter k+2
            half8 Gc0 = {}, Gc1 = {};
            if (k + 2 < nit) {
                Gc0 = vin8[((unsigned)Rc0.x & 0xffffu) * 4 + sub];
                Gc1 = vin8[((unsigned)Rc1.x & 0xffffu) * 4 + sub];
            }
            // stage 3: DS the current iter
            int C0 = (unsigned)Ra0.x >> 16, C1 = (unsigned)Ra1.x >> 16;
            float W0 = __int_as_float(Ra0.y) * wscale;
            float W1 = __int_as_float(Ra1.y) * wscale;
            SPMM_DS2(C0, W0, Ga0, C1, W1, Ga1);
            // rotate windows
            Ra0 = Rb0; Ra1 = Rb1; Rb0 = Rc0; Rb1 = Rc1; Rc0 = Rd0; Rc1 = Rd1;
            Ga0 = Gb0; Ga1 = Gb1; Gb0 = Gc0; Gb1 = Gc1;
            i += 128;
        }
    }
    __syncthreads();
    int base = b << 5;
    int nl = threadIdx.x >> 3, s4 = threadIdx.x & 7;
    int n = base + nl;
    if (n < NN) {
        const int* a = &acc[nl][s4 * 4];
        float4 o = make_float4((float)a[0] * INV_SCALE_W, (float)a[1] * INV_SCALE_W,
                               (float)a[2] * INV_SCALE_W, (float)a[3] * INV_SCALE_W);
        if (vout) ((float4*)vout)[n * 8 + s4] = o;  // fp32 chain (only when read later)
        half4v oh = {(_Float16)o.x, (_Float16)o.y, (_Float16)o.z, (_Float16)o.w};
        *(half4v*)(vout16 + n * 32 + s4 * 4) = oh;  // fp16 gather/epi mirror
    }
}

// ---------------- epi1: MFMA GEMM (64 nodes x 64 outs x K=160) + GRU --------
// Inputs are fp16 mirrors; stage half8 directly into LDS (no convert).
__global__ __launch_bounds__(256) void k_epi1(
    const _Float16* __restrict__ x16, const _Float16* __restrict__ t1,
    const _Float16* __restrict__ t2, const _Float16* __restrict__ t3,
    const _Float16* __restrict__ t4, const float* __restrict__ Wx1,
    const float* __restrict__ bx1, const float* __restrict__ bh1,
    float* __restrict__ h, _Float16* __restrict__ h16) {
    __shared__ _Float16 T[5][MT][40];   // 25.6 KB
    __shared__ _Float16 Wt[64][168];    // 21.5 KB, [n][k]
    int n0 = blockIdx.x * MT;
    const _Float16* bufs[5] = {x16, t1, t2, t3, t4};
#pragma unroll
    for (int b = 0; b < 5; b++) {
        for (int idx = threadIdx.x; idx < MT * 4; idx += 256) {
            int r = idx >> 2, c8 = idx & 3;
            int rr = n0 + r; if (rr >= NN) rr = NN - 1;
            half8 v = *(const half8*)(bufs[b] + rr * 32 + c8 * 8);
            *(half8*)&T[b][r][c8 * 8] = v;
        }
    }
    const float* Wz = Wx1;
    const float* Wh = Wx1 + 2 * KORD * 32 * 32;
    for (int idx = threadIdx.x; idx < 160 * 64; idx += 256) {
        int k = idx >> 6, n = idx & 63;
        int b = k >> 5, i = k & 31;
        float w = (n < 32) ? Wz[b * 1024 + i * 32 + n]
                           : Wh[b * 1024 + i * 32 + (n - 32)];
        Wt[n][k] = (_Float16)w;
    }
    __syncthreads();
    int wave = threadIdx.x >> 6;
    int lane = threadIdx.x & 63;
    int lo = lane & 15, quad = lane >> 4;
    float4v acc[4];
#pragma unroll
    for (int t = 0; t < 4; t++) acc[t] = (float4v){0.f, 0.f, 0.f, 0.f};
#pragma unroll
    for (int b = 0; b < 5; b++) {
        half8 a = *(half8*)&T[b][wave * 16 + lo][quad * 8];
#pragma unroll
        for (int t = 0; t < 4; t++) {
            half8 bf = *(half8*)&Wt[t * 16 + lo][b * 32 + quad * 8];
            acc[t] = __builtin_amdgcn_mfma_f32_16x16x32_f16(a, bf, acc[t], 0, 0, 0);
        }
    }
    int nd_base = n0 + wave * 16 + quad * 4;
#pragma unroll
    for (int t = 0; t < 2; t++) {
        int j = t * 16 + lo;
        float bz = bx1[j] + bh1[j];
        float bhb = bx1[64 + j] + bh1[64 + j];
#pragma unroll
        for (int reg = 0; reg < 4; reg++) {
            int nd = nd_base + reg;
            if (nd < NN) {
                float zz = acc[t][reg] + bz;
                float hh = acc[t + 2][reg] + bhb;
                float z = 1.f / (1.f + __expf(-zz));
                float tt = __expf(-2.f * fabsf(hh));
                float ht = copysignf((1.f - tt) / (1.f + tt), hh);
                float v = fmaxf((1.f - z) * ht, 0.f);
                h[nd * 32 + j] = v;
                h16[nd * 32 + j] = (_Float16)v;
            }
        }
    }
}

// ---------------- epi2: MFMA GEMM (64 x 32 x 160) + GRU + final linear ------
__global__ __launch_bounds__(256) void k_epi2(
    const _Float16* __restrict__ h16, const _Float16* __restrict__ t1,
    const _Float16* __restrict__ t2, const _Float16* __restrict__ t3,
    const _Float16* __restrict__ t4, const float* __restrict__ Wx2,
    const float* __restrict__ bx2, const float* __restrict__ bh2,
    const float* __restrict__ Wl, const float* __restrict__ bl,
    float* __restrict__ out) {
    __shared__ _Float16 T[5][MT][40];   // 25.6 KB
    __shared__ _Float16 Wt[32][168];    // 10.8 KB
    __shared__ float H2[MT][17];
    int n0 = blockIdx.x * MT;
    const _Float16* bufs[5] = {h16, t1, t2, t3, t4};
#pragma unroll
    for (int b = 0; b < 5; b++) {
        for (int idx = threadIdx.x; idx < MT * 4; idx += 256) {
            int r = idx >> 2, c8 = idx & 3;
            int rr = n0 + r; if (rr >= NN) rr = NN - 1;
            half8 v = *(const half8*)(bufs[b] + rr * 32 + c8 * 8);
            *(half8*)&T[b][r][c8 * 8] = v;
        }
    }
    const float* Wz = Wx2;
    const float* Wh = Wx2 + 2 * KORD * 32 * 16;
    for (int idx = threadIdx.x; idx < 160 * 32; idx += 256) {
        int k = idx >> 5, n = idx & 31;
        int b = k >> 5, i = k & 31;
        float w = (n < 16) ? Wz[b * 512 + i * 16 + n]
                           : Wh[b * 512 + i * 16 + (n - 16)];
        Wt[n][k] = (_Float16)w;
    }
    __syncthreads();
    int wave = threadIdx.x >> 6;
    int lane = threadIdx.x & 63;
    int lo = lane & 15, quad = lane >> 4;
    float4v acc[2];
    acc[0] = (float4v){0.f, 0.f, 0.f, 0.f};
    acc[1] = (float4v){0.f, 0.f, 0.f, 0.f};
#pragma unroll
    for (int b = 0; b < 5; b++) {
        half8 a = *(half8*)&T[b][wave * 16 + lo][quad * 8];
#pragma unroll
        for (int t = 0; t < 2; t++) {
            half8 bf = *(half8*)&Wt[t * 16 + lo][b * 32 + quad * 8];
            acc[t] = __builtin_amdgcn_mfma_f32_16x16x32_f16(a, bf, acc[t], 0, 0, 0);
        }
    }
    {
        int j = lo;
        float bz = bx2[j] + bh2[j];
        float bhb = bx2[32 + j] + bh2[32 + j];
        int ndl_base = wave * 16 + quad * 4;
#pragma unroll
        for (int reg = 0; reg < 4; reg++) {
            float zz = acc[0][reg] + bz;
            float hh = acc[1][reg] + bhb;
            float z = 1.f / (1.f + __expf(-zz));
            float tt = __expf(-2.f * fabsf(hh));
            float ht = copysignf((1.f - tt) / (1.f + tt), hh);
            H2[ndl_base + reg][j] = fmaxf((1.f - z) * ht, 0.f);
        }
    }
    __syncthreads();
    for (int idx = threadIdx.x; idx < MT * 12; idx += 256) {
        int n = idx / 12, p = idx % 12;
        int gn = n0 + n;
        if (gn < NN) {
            float o = bl[p];
#pragma unroll
            for (int jj = 0; jj < 16; jj++) o = fmaf(H2[n][jj], Wl[p * 16 + jj], o);
            out[gn * 12 + p] = o;
        }
    }
}

// ---------------- launch ----------------

extern "C" void kernel_launch(void* const* d_in, const int* in_sizes, int n_in,
                              void* d_out, int out_size, void* d_ws, size_t ws_size,
                              hipStream_t stream) {
    const float* x   = (const float*)d_in[0];
    const int*   ei  = (const int*)d_in[1];
    const float* ew  = (const float*)d_in[2];
    const float* Wx1 = (const float*)d_in[3];
    const float* bx1 = (const float*)d_in[4];
    const float* bh1 = (const float*)d_in[6];
    const float* Wx2 = (const float*)d_in[7];
    const float* bx2 = (const float*)d_in[8];
    const float* bh2 = (const float*)d_in[10];
    const float* Wl  = (const float*)d_in[11];
    const float* bl  = (const float*)d_in[12];
    float* out = (float*)d_out;

    float* ws     = (float*)d_ws;
    float* dis    = ws;                         // 50048 floats
    int*   bh     = (int*)(ws + 50048);         // NCH*NBP = 409600 ints
    int*   tot    = bh + NCH * NBP;             // NBP ints
    int*   off_bk = tot + NBP;                  // NBP ints
    int2*  edges  = (int2*)(off_bk + NBP);      // PADE int2 (padded buckets)
    float* T1     = (float*)(edges + PADE);     // fp32 chain buffers
    float* T2     = T1 + NN * 32;
    float* T3     = T2 + NN * 32;
    float* hb     = T3 + NN * 32;
    _Float16* x16 = (_Float16*)(hb + NN * 32);  // fp16 mirrors
    _Float16* t1h = x16 + NN * 32;
    _Float16* t2h = t1h + NN * 32;
    _Float16* t3h = t2h + NN * 32;
    _Float16* t4h = t3h + NN * 32;
    _Float16* hbh = t4h + NN * 32;
    int*   deg_g  = (int*)T1;  // 256*QTR ints (T1+T2 region, dead before spmm)

    k_degbh     <<<512, 1024, 0, stream>>>(ei, ew, deg_g, bh);
    k_btotdiscvt<<<7 + NB + CVB, 256, 0, stream>>>(bh, tot, deg_g, dis, x, x16);
    k_bscan1    <<<1, 1024, 0, stream>>>(tot, off_bk);
    k_curpad    <<<7 + NBK, 256, 0, stream>>>(bh, off_bk, tot, edges);
    k_cperm     <<<NCH, 1024, 0, stream>>>(ei, ew, dis, bh, edges);

    // ---- cell 1: v = x ----  (T3 fp32 is never read -> skip its write)
    k_spmm<<<NBK, 256, 0, stream>>>(off_bk, edges, x16, nullptr, T1, t1h, 1.f);
    k_spmm<<<NBK, 256, 0, stream>>>(off_bk, edges, t1h, x,      T2, t2h, 2.f);
    k_spmm<<<NBK, 256, 0, stream>>>(off_bk, edges, t2h, T1, nullptr, t3h, 2.f);
    k_spmm<<<NBK, 256, 0, stream>>>(off_bk, edges, t3h, T2, nullptr, t4h, 2.f);
    k_epi1<<<GE, 256, 0, stream>>>(x16, t1h, t2h, t3h, t4h, Wx1, bx1, bh1, hb, hbh);

    // ---- cell 2: v = hb ----
    k_spmm<<<NBK, 256, 0, stream>>>(off_bk, edges, hbh, nullptr, T1, t1h, 1.f);
    k_spmm<<<NBK, 256, 0, stream>>>(off_bk, edges, t1h, hb,     T2, t2h, 2.f);
    k_spmm<<<NBK, 256, 0, stream>>>(off_bk, edges, t2h, T1, nullptr, t3h, 2.f);
    k_spmm<<<NBK, 256, 0, stream>>>(off_bk, edges, t3h, T2, nullptr, t4h, 2.f);
    k_epi2<<<GE, 256, 0, stream>>>(hbh, t1h, t2h, t3h, t4h, Wx2, bx2, bh2, Wl, bl, out);
}